// Round 10
// baseline (181.791 us; speedup 1.0000x reference)
//
#include <hip/hip_runtime.h>
#include <hip/hip_bf16.h>

#define B_  8
#define Q_  32
#define LE_ 128
#define D_  512
#define P_  32
#define A_  128

typedef __attribute__((ext_vector_type(8))) short short8_t;   // 8 bf16 (4 VGPRs)
typedef __attribute__((ext_vector_type(4))) float floatx4_t;  // 4 fp32 acc

typedef const __attribute__((address_space(1))) unsigned int glb_uint;
typedef __attribute__((address_space(3))) unsigned int lds_uint;
#define GLD16(g, s) __builtin_amdgcn_global_load_lds((glb_uint*)(g), (lds_uint*)(s), 16, 0, 0)

// fp32 -> bf16 round-to-nearest-even, raw bits
__device__ __forceinline__ short f2bf(float x) {
    unsigned u = __float_as_uint(x);
    unsigned r = (u + 0x7fffu + ((u >> 16) & 1u)) >> 16;
    return (short)r;
}
__device__ __forceinline__ float bf2f(short s) {
    return __uint_as_float(((unsigned)(unsigned short)s) << 16);
}

// ---------------- K0: convert X -> Xb (row) + XbT (transposed), W -> Wb ----------
#define TP_ 136   // LDS transpose tile row pad (shorts)
__global__ __launch_bounds__(256) void convert_kernel(
    const float* __restrict__ X, const float* __restrict__ W,
    short* __restrict__ Xb, short* __restrict__ XbT, short* __restrict__ Wb) {
    int blk = blockIdx.x;
    int tid = threadIdx.x;
    if (blk >= 1024) {
        size_t base = (size_t)(blk - 1024) * 2048 + tid * 8;
        float4 v0 = ((const float4*)(W + base))[0];
        float4 v1 = ((const float4*)(W + base))[1];
        short8_t s;
        s[0] = f2bf(v0.x); s[1] = f2bf(v0.y); s[2] = f2bf(v0.z); s[3] = f2bf(v0.w);
        s[4] = f2bf(v1.x); s[5] = f2bf(v1.y); s[6] = f2bf(v1.z); s[7] = f2bf(v1.w);
        *(short8_t*)(Wb + base) = s;
        return;
    }
    __shared__ short tile[128 * TP_];
    int bq = blk >> 2, d0 = (blk & 3) * 128;
    int tt = tid >> 5, dd = (tid & 31) * 4;
#pragma unroll 4
    for (int pass = 0; pass < 16; ++pass) {
        int t = tt + pass * 8;
        float4 v = *(const float4*)(X + (size_t)(bq * LE_ + t) * D_ + d0 + dd);
        unsigned s0 = (unsigned short)f2bf(v.x), s1 = (unsigned short)f2bf(v.y);
        unsigned s2 = (unsigned short)f2bf(v.z), s3 = (unsigned short)f2bf(v.w);
        uint2 pk;
        pk.x = s0 | (s1 << 16);
        pk.y = s2 | (s3 << 16);
        *(uint2*)(Xb + (size_t)(bq * LE_ + t) * D_ + d0 + dd) = pk;
        tile[(dd + 0) * TP_ + t] = (short)s0;
        tile[(dd + 1) * TP_ + t] = (short)s1;
        tile[(dd + 2) * TP_ + t] = (short)s2;
        tile[(dd + 3) * TP_ + t] = (short)s3;
    }
    __syncthreads();
    int dr = tid >> 1, th = (tid & 1) * 64;
    short* dst = XbT + ((size_t)(bq * D_) + d0 + dr) * LE_ + th;
#pragma unroll
    for (int i = 0; i < 8; ++i)
        *(short8_t*)(dst + i * 8) = *(const short8_t*)(tile + dr * TP_ + th + i * 8);
}

// ---------------- K1: EW[b,p,a] = exp(2*(s_j[b,p,:]·Ws_w[a,:] + Ws_b[a])) -------
__global__ __launch_bounds__(128) void ws_kernel(
    const float* __restrict__ s_j, const float* __restrict__ Ws_w,
    const float* __restrict__ Ws_b, float* __restrict__ ws) {
    __shared__ float s_row[D_];
    int bp = blockIdx.x;
    const float* src = s_j + (size_t)bp * D_;
    for (int i = threadIdx.x; i < D_; i += 128) s_row[i] = src[i];
    __syncthreads();
    int a = threadIdx.x;
    const float4* w4 = (const float4*)(Ws_w + (size_t)a * D_);
    const float4* s4 = (const float4*)s_row;
    float acc = 0.0f;
#pragma unroll 8
    for (int i = 0; i < D_ / 4; ++i) {
        float4 w = w4[i];
        float4 s = s4[i];
        acc += w.x * s.x + w.y * s.y + w.z * s.z + w.w * s.w;
    }
    ws[bp * A_ + a] = __expf(2.0f * (acc + Ws_b[a]));
}

// ---------------- K2: FUSED per-bq kernel ----------------------------------------
// 64 KB LDS arena, phase-disjoint:
//   phase1 (uh GEMM, BK=128): A stg [0,32KB), B stg [32KB,64KB)
//   phase2/3 (score): EU [0,34816), ew [34816,51712), w_s [51712,60416),
//                     n2v [60416,60928), mask [60928,61440)
//   phase4 (PV): pvB [0,32768), w_s kept
#define EUP_ 136
#define EWP_ 132
#define WPP_ 136

__global__ __launch_bounds__(512, 1) void fused_kernel(
    const short* __restrict__ Xb, const short* __restrict__ Wb,
    const short* __restrict__ XbT,
    const float* __restrict__ EW, const float* __restrict__ v_w,
    const int* __restrict__ exp_mask, float* __restrict__ gsums,
    float* __restrict__ out) {
    __shared__ __align__(16) char arena[65536];
    short* stgA  = (short*)arena;              // 16384 shorts
    short* stgB  = (short*)(arena + 32768);    // 16384 shorts
    short* EU    = (short*)arena;              // 128 x EUP_
    float* ew_s  = (float*)(arena + 34816);    // 32 x EWP_
    short* w_s   = (short*)(arena + 51712);    // 32 x WPP_
    float* n2v   = (float*)(arena + 60416);    // 128
    int*   mask_s= (int*)(arena + 60928);      // 128
    short* pvB   = (short*)arena;              // 128 x 128

    int bq = blockIdx.x;
    int b  = bq >> 5;
    int tid = threadIdx.x;
    int wave = tid >> 6, lane = tid & 63;
    int qd = lane >> 4, lr = lane & 15;

    // ---- phase 1: uh GEMM (C = 128t x 128a, K = 512, BK = 128) ----
    int m0 = (wave >> 1) * 32, n0 = (wave & 1) * 64;
    int rsub = lane >> 4;          // row within 4-row GLD16 issue
    int slot = lane & 15;

    floatx4_t acc[2][4];
#pragma unroll
    for (int i = 0; i < 2; ++i)
#pragma unroll
        for (int j = 0; j < 4; ++j) acc[i][j] = (floatx4_t){0.f, 0.f, 0.f, 0.f};

    for (int kt = 0; kt < 4; ++kt) {
        int k0 = kt * 128;
        __syncthreads();
#pragma unroll
        for (int u = 0; u < 4; ++u) {
            int row = wave * 16 + u * 4 + rsub;
            int sc = (slot ^ (row & 15)) * 8;
            GLD16(Xb + (size_t)(bq * 128 + row) * D_ + k0 + sc,
                  stgA + (wave * 16 + u * 4) * 128);
            GLD16(Wb + (size_t)row * D_ + k0 + sc,
                  stgB + (wave * 16 + u * 4) * 128);
        }
        __syncthreads();
#pragma unroll
        for (int ks = 0; ks < 4; ++ks) {
            int co = ((ks * 4 + qd) ^ lr) * 8;
            short8_t af[2], bfr[4];
#pragma unroll
            for (int i = 0; i < 2; ++i)
                af[i] = *(const short8_t*)(stgA + (m0 + i * 16 + lr) * 128 + co);
#pragma unroll
            for (int j = 0; j < 4; ++j)
                bfr[j] = *(const short8_t*)(stgB + (n0 + j * 16 + lr) * 128 + co);
#pragma unroll
            for (int i = 0; i < 2; ++i)
#pragma unroll
                for (int j = 0; j < 4; ++j)
                    acc[i][j] = __builtin_amdgcn_mfma_f32_16x16x32_bf16(af[i], bfr[j], acc[i][j], 0, 0, 0);
        }
    }
    __syncthreads();   // staging dead -> EU region

    // ---- phase 2: EU = bf16(exp(2 uh)) -> LDS; load ew / n2v / mask ----
#pragma unroll
    for (int i = 0; i < 2; ++i)
#pragma unroll
        for (int j = 0; j < 4; ++j)
#pragma unroll
            for (int r = 0; r < 4; ++r) {
                int t = m0 + i * 16 + qd * 4 + r;
                int a = n0 + j * 16 + lr;
                EU[t * EUP_ + a] = f2bf(__expf(2.0f * acc[i][j][r]));
            }
#pragma unroll
    for (int u = 0; u < 2; ++u) {
        int c = tid * 2 + u;              // 1024 float4
        int p = c >> 5, seg = c & 31;
        *(float4*)&ew_s[p * EWP_ + seg * 4] =
            *(const float4*)&EW[(size_t)(b * P_ + p) * A_ + seg * 4];
    }
    if (tid < 32) {
        float4 v = *(const float4*)(v_w + tid * 4);
        v.x *= -2.0f; v.y *= -2.0f; v.z *= -2.0f; v.w *= -2.0f;
        *(float4*)&n2v[tid * 4] = v;
    }
    if (tid < 128) mask_s[tid] = exp_mask[bq * LE_ + tid];
    __syncthreads();

    // ---- phase 3: score ----
    {
        int t = tid & 127, pg = tid >> 7;
        float acc8[8];
#pragma unroll
        for (int j = 0; j < 8; ++j) acc8[j] = 0.0f;
        for (int a8 = 0; a8 < 16; ++a8) {
            short8_t e8 = *(const short8_t*)&EU[t * EUP_ + a8 * 8];
            float eu[8];
#pragma unroll
            for (int k = 0; k < 8; ++k) eu[k] = bf2f(e8[k]);
            float4 nv0 = *(const float4*)&n2v[a8 * 8];
            float4 nv1 = *(const float4*)&n2v[a8 * 8 + 4];
            float nv[8] = {nv0.x, nv0.y, nv0.z, nv0.w, nv1.x, nv1.y, nv1.z, nv1.w};
#pragma unroll
            for (int j = 0; j < 8; ++j) {
                int p = pg * 8 + j;
                float4 w0 = *(const float4*)&ew_s[p * EWP_ + a8 * 8];
                float4 w1 = *(const float4*)&ew_s[p * EWP_ + a8 * 8 + 4];
                float ww[8] = {w0.x, w0.y, w0.z, w0.w, w1.x, w1.y, w1.z, w1.w};
#pragma unroll
                for (int k = 0; k < 8; ++k)
                    acc8[j] = fmaf(nv[k], __builtin_amdgcn_rcpf(fmaf(eu[k], ww[k], 1.0f)), acc8[j]);
            }
        }
        int mk = mask_s[t];
#pragma unroll
        for (int j = 0; j < 8; ++j) {
            float ee = mk ? __expf(acc8[j]) : 0.0f;
            w_s[(pg * 8 + j) * WPP_ + t] = f2bf(ee);
        }
    }
    __syncthreads();   // w_s ready; EU dead -> pvB

    // ---- phase 4 staging helper (chunk = 128 d columns) ----
    auto stage4 = [&](int chunk) {
#pragma unroll
        for (int u = 0; u < 4; ++u) {
            int row = wave * 16 + u * 4 + rsub;     // d within chunk
            int sc = (slot ^ (row & 15)) * 8;
            GLD16(XbT + ((size_t)(bq * D_) + chunk * 128 + row) * LE_ + sc,
                  pvB + (wave * 16 + u * 4) * 128);
        }
    };
    stage4(0);

    // ---- sums: per-p reduce of w_s (overlaps chunk-0 DMA) ----
    if (tid < 256) {
        int p = tid >> 3, seg = tid & 7;
        const short* src = w_s + p * WPP_ + seg * 16;
        float s = 0.0f;
#pragma unroll
        for (int k = 0; k < 16; ++k) s += bf2f(src[k]);
        s += __shfl_xor(s, 1);
        s += __shfl_xor(s, 2);
        s += __shfl_xor(s, 4);
        if (seg == 0) atomicAdd(&gsums[b * P_ + p], s);
    }

    // A fragments (w_s) for PV
    short8_t afv[2][4];
#pragma unroll
    for (int i = 0; i < 2; ++i)
#pragma unroll
        for (int ks = 0; ks < 4; ++ks)
            afv[i][ks] = *(const short8_t*)&w_s[(i * 16 + lr) * WPP_ + ks * 32 + qd * 8];

    // ---- phase 4: out_un[p][d] = sum_t w[p][t] * XbT[d][t] ----
    for (int chunk = 0; chunk < 4; ++chunk) {
        __syncthreads();   // staged chunk visible
        floatx4_t accp[2];
        accp[0] = (floatx4_t){0.f, 0.f, 0.f, 0.f};
        accp[1] = (floatx4_t){0.f, 0.f, 0.f, 0.f};
#pragma unroll
        for (int ks = 0; ks < 4; ++ks) {
            int co = ((ks * 4 + qd) ^ lr) * 8;
            short8_t bfr = *(const short8_t*)&pvB[(wave * 16 + lr) * 128 + co];
            accp[0] = __builtin_amdgcn_mfma_f32_16x16x32_bf16(afv[0][ks], bfr, accp[0], 0, 0, 0);
            accp[1] = __builtin_amdgcn_mfma_f32_16x16x32_bf16(afv[1][ks], bfr, accp[1], 0, 0, 0);
        }
#pragma unroll
        for (int i = 0; i < 2; ++i)
#pragma unroll
            for (int r = 0; r < 4; ++r) {
                int p = i * 16 + qd * 4 + r;
                out[((size_t)bq * P_ + p) * D_ + chunk * 128 + wave * 16 + lr] = accp[i][r];
            }
        if (chunk < 3) {
            __syncthreads();   // all reads of pvB done
            stage4(chunk + 1);
        }
    }
}

// ---------------- K3: normalize: out[bq,p,:] *= req_mask/gsums -------------------
__global__ __launch_bounds__(256) void norm_kernel(
    float* __restrict__ out, const float* __restrict__ gsums,
    const int* __restrict__ req_mask) {
    int bqp = blockIdx.x;            // 8192 = bq*32 + p
    int p = bqp & 31;
    int b = bqp >> 10;
    int bp = b * P_ + p;
    float s = gsums[bp];
    float rm = req_mask[bp] ? __fdividef(1.0f, s) : 0.0f;
    float2* o = (float2*)(out + (size_t)bqp * D_);
    float2 v = o[threadIdx.x];
    v.x *= rm; v.y *= rm;
    o[threadIdx.x] = v;
}

extern "C" void kernel_launch(void* const* d_in, const int* in_sizes, int n_in,
                              void* d_out, int out_size, void* d_ws, size_t ws_size,
                              hipStream_t stream) {
    const float* exp_tokens = (const float*)d_in[0];
    const int*   exp_mask   = (const int*)d_in[1];
    const float* s_j        = (const float*)d_in[2];
    const int*   req_mask   = (const int*)d_in[3];
    const float* Ws_w       = (const float*)d_in[4];
    const float* Ws_b       = (const float*)d_in[5];
    const float* U_w        = (const float*)d_in[6];
    const float* v_w        = (const float*)d_in[7];
    float* out = (float*)d_out;

    float* EW    = (float*)d_ws;                          // 32768 floats
    float* gsums = EW + B_ * P_ * A_;                     // 256 floats
    short* Xb    = (short*)(gsums + 256);                 // 16.7M shorts
    short* XbT   = Xb + (size_t)B_ * Q_ * LE_ * D_;       // 16.7M shorts
    short* Wb    = XbT + (size_t)B_ * Q_ * LE_ * D_;      // 64K shorts

    hipMemsetAsync(gsums, 0, B_ * P_ * sizeof(float), stream);
    convert_kernel<<<dim3(1024 + 32), dim3(256), 0, stream>>>(exp_tokens, U_w, Xb, XbT, Wb);
    ws_kernel<<<dim3(B_ * P_), dim3(128), 0, stream>>>(s_j, Ws_w, Ws_b, EW);
    fused_kernel<<<dim3(B_ * Q_), dim3(512), 0, stream>>>(Xb, Wb, XbT, EW, v_w, exp_mask, gsums, out);
    norm_kernel<<<dim3(B_ * Q_ * P_), dim3(256), 0, stream>>>(out, gsums, req_mask);
}